// Round 4
// baseline (354.562 us; speedup 1.0000x reference)
//
#include <hip/hip_runtime.h>

// CapsuleNet forward, fused, fp32 — R4: R3 minus the spill-inducing
// __launch_bounds__ min-waves arg. (768,6) forced VGPR<=85 and the compiler
// spilled P0/P1 to scratch (WRITE_SIZE 105 MB, 10x the output). Unconstrained,
// this structure compiles to ~60 VGPR (proven in R1) -> no spill, and the
// 80 KB LDS footprint still allows 2 blocks/CU (proven by R3's 65% occupancy).
constexpr int OC = 10, NI = 36, OD = 16, IL = 8;
constexpr int M_BLK   = 8;             // batches per block
constexpr int M_INNER = 2;             // batches per routing pass
constexpr int NGROUPS = M_BLK / M_INNER;   // 4
constexpr int NT      = 768;
constexpr int SROW = 20;   // spl row stride: 8 uniform b128 start banks
constexpr int CROW = 12;   // caps row stride: 16B-aligned, 8 start banks
constexpr int PROW = 36;   // ptab row stride

__global__ __launch_bounds__(NT)
void capsnet_kernel(const float* __restrict__ xg,
                    const float* __restrict__ cwg,
                    const float* __restrict__ lwg,
                    float* __restrict__ outg) {
    __shared__ float xs[M_BLK * 9];                    //   288 B
    __shared__ float cw[288];                          //  1152 B
    __shared__ float caps_s[M_BLK * NI * CROW];        // 13824 B
    __shared__ float spl[M_INNER * OC * NI * SROW];    // 57600 B raw priors
    __shared__ float el[M_INNER * NI * OC];            //  2880 B exp(logits)
    __shared__ float ptab[M_INNER * OC * PROW];        //  2880 B coupling p
    __shared__ float outl[M_INNER * OC * OD];          //  1280 B
    // total ~79.9 KB -> 2 blocks/CU

    const int t  = threadIdx.x;
    const int b0 = blockIdx.x * M_BLK;

    if (t < M_BLK * 9) xs[t] = xg[b0 * 9 + t];
    if (t < 288)       cw[t] = cwg[t];

    const bool act = t < 2 * OC * NI;   // 720
    const int o  = t / 72;
    const int r  = t % 72;
    const int i  = r >> 1;
    const int dh = r & 1;
    __syncthreads();

    // ---- conv (1->32ch, 3x3, pad 1) + squash -> caps_s ----
    if (t < M_BLK * NI) {   // 288
        const int m  = t / NI;
        const int ci = t % NI;
        const int cg = ci & 3;
        const int wx = (ci >> 2) % 3;
        const int hx = ci / 12;
        float acc[IL] = {0.f,0.f,0.f,0.f,0.f,0.f,0.f,0.f};
        #pragma unroll
        for (int kh = 0; kh < 3; ++kh) {
            const int xh = hx + kh - 1;
            if (xh < 0 || xh > 2) continue;
            #pragma unroll
            for (int kw = 0; kw < 3; ++kw) {
                const int xw = wx + kw - 1;
                if (xw < 0 || xw > 2) continue;
                const float xv = xs[m * 9 + xh * 3 + xw];
                #pragma unroll
                for (int l = 0; l < IL; ++l)
                    acc[l] += xv * cw[(cg * 8 + l) * 9 + kh * 3 + kw];
            }
        }
        float n2 = 0.f;
        #pragma unroll
        for (int l = 0; l < IL; ++l) n2 += acc[l] * acc[l];
        const float sc = n2 / (1.f + n2) * rsqrtf(n2 + 1e-8f);
        float4* cp = reinterpret_cast<float4*>(caps_s + (m * NI + ci) * CROW);
        cp[0] = make_float4(acc[0]*sc, acc[1]*sc, acc[2]*sc, acc[3]*sc);
        cp[1] = make_float4(acc[4]*sc, acc[5]*sc, acc[6]*sc, acc[7]*sc);
    }
    __syncthreads();

    for (int grp = 0; grp < NGROUPS; ++grp) {
        float P0[8], P1[8];
        float lg0 = 0.f, lg1 = 0.f;
        // ---- einsum (weights streamed from L2) + raw-P write to spl ----
        if (act) {
            const float4* cpa = reinterpret_cast<const float4*>(
                caps_s + ((grp * 2 + 0) * NI + i) * CROW);
            const float4* cpb = reinterpret_cast<const float4*>(
                caps_s + ((grp * 2 + 1) * NI + i) * CROW);
            const float4 c00 = cpa[0], c01 = cpa[1];
            const float4 c10 = cpb[0], c11 = cpb[1];
            const float4* wp = reinterpret_cast<const float4*>(
                lwg + ((o * NI + i) * OD + dh * 8) * IL);
            #pragma unroll
            for (int d = 0; d < 8; ++d) {
                const float4 a = wp[2*d], b = wp[2*d + 1];
                P0[d] = a.x*c00.x + a.y*c00.y + a.z*c00.z + a.w*c00.w
                      + b.x*c01.x + b.y*c01.y + b.z*c01.z + b.w*c01.w;
                P1[d] = a.x*c10.x + a.y*c10.y + a.z*c10.z + a.w*c10.w
                      + b.x*c11.x + b.y*c11.y + b.z*c11.z + b.w*c11.w;
            }
            float4* sp0 = reinterpret_cast<float4*>(
                spl + ((0 * OC + o) * NI + i) * SROW + dh * 8);
            float4* sp1 = reinterpret_cast<float4*>(
                spl + ((1 * OC + o) * NI + i) * SROW + dh * 8);
            sp0[0] = make_float4(P0[0], P0[1], P0[2], P0[3]);
            sp0[1] = make_float4(P0[4], P0[5], P0[6], P0[7]);
            sp1[0] = make_float4(P1[0], P1[1], P1[2], P1[3]);
            sp1[1] = make_float4(P1[4], P1[5], P1[6], P1[7]);
        }
        __syncthreads();   // B1: spl ready

        for (int it = 0; it < 3; ++it) {
            // ---- reduce over i + squash: 160 threads (mo, dq, ih) ----
            if (t < M_INNER * OC * 8) {   // 160
                const int mo = t >> 3;          // m*10+o
                const int dq = (t >> 1) & 3;
                const int ih = t & 1;
                const float* base = spl + mo * NI * SROW + dq * 4;
                float4 s4 = make_float4(0.f, 0.f, 0.f, 0.f);
                if (it == 0) {
                    #pragma unroll
                    for (int ii = 0; ii < 18; ++ii) {
                        const float4 v = *reinterpret_cast<const float4*>(
                            base + (ih * 18 + ii) * SROW);
                        s4.x += v.x; s4.y += v.y; s4.z += v.z; s4.w += v.w;
                    }
                    s4.x *= 0.1f; s4.y *= 0.1f; s4.z *= 0.1f; s4.w *= 0.1f;
                } else {
                    const float* pr = ptab + mo * PROW;
                    #pragma unroll
                    for (int ii = 0; ii < 18; ++ii) {
                        const float pv = pr[ih * 18 + ii];
                        const float4 v = *reinterpret_cast<const float4*>(
                            base + (ih * 18 + ii) * SROW);
                        s4.x += pv * v.x; s4.y += pv * v.y;
                        s4.z += pv * v.z; s4.w += pv * v.w;
                    }
                }
                // reduce over ih (lane bit 0)
                s4.x += __shfl_xor(s4.x, 1);
                s4.y += __shfl_xor(s4.y, 1);
                s4.z += __shfl_xor(s4.z, 1);
                s4.w += __shfl_xor(s4.w, 1);
                float n2 = s4.x*s4.x + s4.y*s4.y + s4.z*s4.z + s4.w*s4.w;
                n2 += __shfl_xor(n2, 2);   // dq bits are lane bits 1-2
                n2 += __shfl_xor(n2, 4);
                const float sc = n2 / (1.f + n2) * rsqrtf(n2 + 1e-8f);
                const float4 ov = make_float4(s4.x*sc, s4.y*sc, s4.z*sc, s4.w*sc);
                if (ih == 0) {
                    const int rm = mo / 10, ro = mo % 10;
                    if (it == 2)
                        *reinterpret_cast<float4*>(
                            outg + (b0 + grp * 2 + rm) * (OC*OD) + ro * OD + dq * 4) = ov;
                    else
                        *reinterpret_cast<float4*>(
                            outl + rm * (OC*OD) + ro * OD + dq * 4) = ov;
                }
            }
            __syncthreads();   // B2: out ready / spl reads done
            if (it == 2) break;

            // ---- agreement: logits += P . out ; write exp(logits) ----
            if (act) {
                const float4* om0 = reinterpret_cast<const float4*>(
                    outl + 0 * (OC*OD) + o * OD + dh * 8);
                const float4* om1 = reinterpret_cast<const float4*>(
                    outl + 1 * (OC*OD) + o * OD + dh * 8);
                const float4 oa = om0[0], ob = om0[1];
                const float4 oc = om1[0], od4 = om1[1];
                float dp0 = P0[0]*oa.x + P0[1]*oa.y + P0[2]*oa.z + P0[3]*oa.w
                          + P0[4]*ob.x + P0[5]*ob.y + P0[6]*ob.z + P0[7]*ob.w;
                float dp1 = P1[0]*oc.x + P1[1]*oc.y + P1[2]*oc.z + P1[3]*oc.w
                          + P1[4]*od4.x + P1[5]*od4.y + P1[6]*od4.z + P1[7]*od4.w;
                dp0 += __shfl_xor(dp0, 1);   // dh is lane bit 0
                dp1 += __shfl_xor(dp1, 1);
                lg0 += dp0;
                lg1 += dp1;
                if (dh == 0) {
                    el[(0 * NI + i) * OC + o] = __expf(lg0);
                    el[(1 * NI + i) * OC + o] = __expf(lg1);
                }
            }
            __syncthreads();   // B3: el ready

            // ---- softmax over o -> coupling table ptab[m][o][i] ----
            if (t < M_INNER * NI) {   // 72
                const int em = t / NI, ei = t % NI;
                const float* er = el + (em * NI + ei) * OC;
                float ss = 0.f;
                #pragma unroll
                for (int o2 = 0; o2 < OC; ++o2) ss += er[o2];
                const float inv = 1.f / ss;
                #pragma unroll
                for (int o2 = 0; o2 < OC; ++o2)
                    ptab[(em * OC + o2) * PROW + ei] = er[o2] * inv;
            }
            __syncthreads();   // B4: ptab ready
        }
    }
}

extern "C" void kernel_launch(void* const* d_in, const int* in_sizes, int n_in,
                              void* d_out, int out_size, void* d_ws, size_t ws_size,
                              hipStream_t stream) {
    const float* x   = (const float*)d_in[0];   // [B,1,3,3]
    const float* cwp = (const float*)d_in[1];   // [32,1,3,3]
    const float* lw  = (const float*)d_in[2];   // [10,36,16,8]
    float* out = (float*)d_out;                 // [B,10,16]
    const int B = in_sizes[0] / 9;              // 16384
    dim3 grid(B / M_BLK), block(NT);
    capsnet_kernel<<<grid, block, 0, stream>>>(x, cwp, lw, out);
}

// Round 5
// 304.274 us; speedup vs baseline: 1.1653x; 1.1653x over previous
//
#include <hip/hip_runtime.h>

// CapsuleNet forward, fused, fp32 — R5: register-resident dynamic routing.
// Priors transposed through LDS ONCE per batch into (o-wave, lane=(iq,d))
// register layout; all 3 routing iterations run in VGPRs using
// __shfl_xor (i-partial sum over 4 iq lanes) and DPP row_ror allreduce
// (d-sums on the VALU pipe instead of the DS pipe). Per-iter LDS is only
// the tiny softmax-over-o exchange. Einsum keeps R1's proven structure:
// 720 threads (o,i,dh) with lin_w register-resident (16 float4/thread,
// loaded once per block, reused for all 8 batches).
constexpr int OC = 10, NI = 36, OD = 16, IL = 8;
constexpr int M_BLK = 8;     // batches per block
constexpr int NT    = 768;   // 12 waves
constexpr int CROW  = 12;    // caps row stride (16B aligned, 8 b128 start banks)
constexpr int SROW  = 20;    // spl row stride (conflict-free writes AND d-strided reads)

template <int CTRL>
__device__ __forceinline__ float dpp_ror_add(float x) {
    int yi = __builtin_amdgcn_update_dpp(0, __float_as_int(x), CTRL, 0xf, 0xf, false);
    return x + __int_as_float(yi);
}
// sum over the 16 lanes of a DPP row (our d dimension = lane&15)
__device__ __forceinline__ float row16_allreduce(float x) {
    x = dpp_ror_add<0x128>(x);   // row_ror:8
    x = dpp_ror_add<0x124>(x);   // row_ror:4
    x = dpp_ror_add<0x122>(x);   // row_ror:2
    x = dpp_ror_add<0x121>(x);   // row_ror:1
    return x;
}
// sum over the 4 iq replicas (lane bits 4,5)
__device__ __forceinline__ float iq4_allreduce(float x) {
    x += __shfl_xor(x, 16);
    x += __shfl_xor(x, 32);
    return x;
}

__global__ __launch_bounds__(NT)
void capsnet_kernel(const float* __restrict__ xg,
                    const float* __restrict__ cwg,
                    const float* __restrict__ lwg,
                    float* __restrict__ outg) {
    __shared__ float xs[M_BLK * 9];              //  288 B
    __shared__ float cw[288];                    // 1152 B
    __shared__ float caps_s[M_BLK * NI * CROW];  // 13824 B
    __shared__ float spl[2 * OC * NI * SROW];    // 57600 B (batch pair)
    __shared__ float el[2 * OC * NI];            //  2880 B exp(logits)
    __shared__ float sinvp[2 * 64];              //   512 B 1/sum_o exp, iq-padded
    // total ~76.3 KB

    const int t  = threadIdx.x;
    const int b0 = blockIdx.x * M_BLK;

    if (t < M_BLK * 9) xs[t] = xg[b0 * 9 + t];
    if (t < 288)       cw[t] = cwg[t];

    // --- einsum-phase thread mapping: (eo, ei, edh), 720 active ---
    const bool act = t < 2 * OC * NI;
    const int eo  = t / 72;
    const int er  = t % 72;
    const int ei  = er >> 1;
    const int edh = er & 1;

    float4 w4[16];   // lin_w[eo][ei][edh*8..+7][0..7], loaded once, reused 8 batches
    if (act) {
        const float4* wp = reinterpret_cast<const float4*>(
            lwg + ((eo * NI + ei) * OD + edh * 8) * IL);
        #pragma unroll
        for (int j = 0; j < 16; ++j) w4[j] = wp[j];
    }

    // --- routing-phase thread mapping: wave = o, lane = (iq, d), 640 active ---
    const bool ract = t < OC * 64;
    const int ro  = t >> 6;          // wave id = out capsule
    const int lane = t & 63;
    const int rd  = lane & 15;       // d (DPP row dimension)
    const int riq = lane >> 4;       // i quarter: owns i = riq*9 + k

    __syncthreads();

    // ---- conv (1->32ch, 3x3, pad 1) + squash -> caps_s ----
    if (t < M_BLK * NI) {   // 288
        const int m  = t / NI;
        const int ci = t % NI;
        const int cg = ci & 3;
        const int wx = (ci >> 2) % 3;
        const int hx = ci / 12;
        float acc[IL] = {0.f,0.f,0.f,0.f,0.f,0.f,0.f,0.f};
        #pragma unroll
        for (int kh = 0; kh < 3; ++kh) {
            const int xh = hx + kh - 1;
            if (xh < 0 || xh > 2) continue;
            #pragma unroll
            for (int kw = 0; kw < 3; ++kw) {
                const int xw = wx + kw - 1;
                if (xw < 0 || xw > 2) continue;
                const float xv = xs[m * 9 + xh * 3 + xw];
                #pragma unroll
                for (int l = 0; l < IL; ++l)
                    acc[l] += xv * cw[(cg * 8 + l) * 9 + kh * 3 + kw];
            }
        }
        float n2 = 0.f;
        #pragma unroll
        for (int l = 0; l < IL; ++l) n2 += acc[l] * acc[l];
        const float sc = n2 / (1.f + n2) * rsqrtf(n2 + 1e-8f);
        float4* cp = reinterpret_cast<float4*>(caps_s + (m * NI + ci) * CROW);
        cp[0] = make_float4(acc[0]*sc, acc[1]*sc, acc[2]*sc, acc[3]*sc);
        cp[1] = make_float4(acc[4]*sc, acc[5]*sc, acc[6]*sc, acc[7]*sc);
    }
    __syncthreads();

    for (int pr = 0; pr < M_BLK / 2; ++pr) {
        // ---- E: einsum for batch pair -> spl[0], spl[1] ----
        if (act) {
            #pragma unroll
            for (int bp = 0; bp < 2; ++bp) {
                const float4* cp = reinterpret_cast<const float4*>(
                    caps_s + ((pr * 2 + bp) * NI + ei) * CROW);
                const float4 c0 = cp[0], c1 = cp[1];
                float Pv[8];
                #pragma unroll
                for (int d8 = 0; d8 < 8; ++d8) {
                    const float4 a = w4[2*d8], b = w4[2*d8 + 1];
                    Pv[d8] = a.x*c0.x + a.y*c0.y + a.z*c0.z + a.w*c0.w
                           + b.x*c1.x + b.y*c1.y + b.z*c1.z + b.w*c1.w;
                }
                float4* sp = reinterpret_cast<float4*>(
                    spl + bp * OC * NI * SROW + (eo * NI + ei) * SROW + edh * 8);
                sp[0] = make_float4(Pv[0], Pv[1], Pv[2], Pv[3]);
                sp[1] = make_float4(Pv[4], Pv[5], Pv[6], Pv[7]);
            }
        }
        __syncthreads();   // spl ready

        float P[2][9], lg[2][9];
        // ---- T + R0: transpose-read into regs, it0, agreement0, el write ----
        if (ract) {
            #pragma unroll
            for (int bp = 0; bp < 2; ++bp) {
                const float* sb = spl + bp * OC * NI * SROW
                                + (ro * NI + riq * 9) * SROW + rd;
                #pragma unroll
                for (int k = 0; k < 9; ++k) P[bp][k] = sb[k * SROW];
                float tl = 0.f;
                #pragma unroll
                for (int k = 0; k < 9; ++k) tl += P[bp][k];
                const float s  = 0.1f * iq4_allreduce(tl);   // softmax(0) = 1/10
                const float n2 = row16_allreduce(s * s);
                const float sc = n2 / (1.f + n2) * rsqrtf(n2 + 1e-8f);
                const float v  = s * sc;
                #pragma unroll
                for (int k = 0; k < 9; ++k)
                    lg[bp][k] = row16_allreduce(P[bp][k] * v);
                if (rd < 9)
                    el[bp * 360 + ro * NI + riq * 9 + rd] = __expf(lg[bp][rd]);
            }
        }
        __syncthreads();   // el ready
        // ---- S1: softmax denominators ----
        if (t < 72) {
            const int bp = t / NI, i = t % NI;
            float ss = 0.f;
            #pragma unroll
            for (int o2 = 0; o2 < OC; ++o2) ss += el[bp * 360 + o2 * NI + i];
            sinvp[bp * 64 + (i / 9) * 16 + (i % 9)] = 1.f / ss;
        }
        __syncthreads();   // sinv ready
        // ---- R1: it1 + agreement1 + el write ----
        if (ract) {
            #pragma unroll
            for (int bp = 0; bp < 2; ++bp) {
                const float* svp = sinvp + bp * 64 + riq * 16;
                float tl = 0.f;
                #pragma unroll
                for (int k = 0; k < 9; ++k)
                    tl += __expf(lg[bp][k]) * svp[k] * P[bp][k];
                const float s  = iq4_allreduce(tl);
                const float n2 = row16_allreduce(s * s);
                const float sc = n2 / (1.f + n2) * rsqrtf(n2 + 1e-8f);
                const float v  = s * sc;
                #pragma unroll
                for (int k = 0; k < 9; ++k)
                    lg[bp][k] += row16_allreduce(P[bp][k] * v);
                if (rd < 9)
                    el[bp * 360 + ro * NI + riq * 9 + rd] = __expf(lg[bp][rd]);
            }
        }
        __syncthreads();   // el ready
        // ---- S2 ----
        if (t < 72) {
            const int bp = t / NI, i = t % NI;
            float ss = 0.f;
            #pragma unroll
            for (int o2 = 0; o2 < OC; ++o2) ss += el[bp * 360 + o2 * NI + i];
            sinvp[bp * 64 + (i / 9) * 16 + (i % 9)] = 1.f / ss;
        }
        __syncthreads();   // sinv ready
        // ---- R2: it2 + output (no barrier before next pair's einsum:
        //      touches neither spl nor el) ----
        if (ract) {
            #pragma unroll
            for (int bp = 0; bp < 2; ++bp) {
                const float* svp = sinvp + bp * 64 + riq * 16;
                float tl = 0.f;
                #pragma unroll
                for (int k = 0; k < 9; ++k)
                    tl += __expf(lg[bp][k]) * svp[k] * P[bp][k];
                const float s  = iq4_allreduce(tl);
                const float n2 = row16_allreduce(s * s);
                const float sc = n2 / (1.f + n2) * rsqrtf(n2 + 1e-8f);
                const float v  = s * sc;
                if (riq == 0)
                    outg[(b0 + pr * 2 + bp) * (OC * OD) + ro * OD + rd] = v;
            }
        }
    }
}

extern "C" void kernel_launch(void* const* d_in, const int* in_sizes, int n_in,
                              void* d_out, int out_size, void* d_ws, size_t ws_size,
                              hipStream_t stream) {
    const float* x   = (const float*)d_in[0];   // [B,1,3,3]
    const float* cwp = (const float*)d_in[1];   // [32,1,3,3]
    const float* lw  = (const float*)d_in[2];   // [10,36,16,8]
    float* out = (float*)d_out;                 // [B,10,16]
    const int B = in_sizes[0] / 9;              // 16384
    dim3 grid(B / M_BLK), block(NT);
    capsnet_kernel<<<grid, block, 0, stream>>>(x, cwp, lw, out);
}